// Round 1
// baseline (664.952 us; speedup 1.0000x reference)
//
#include <hip/hip_runtime.h>

// Problem constants (fixed by reference)
#define N_TOK 343     // 7*7*7 tokens per window
#define C_DIM 96
#define HEADS 3
#define HD 32
#define B_SZ 256
#define NW 32
#define QKV_COLS 288  // 3*C

#define QKV_ELEMS (B_SZ * HEADS * N_TOK * HD)  // 8429568 per tensor

// ---------------------------------------------------------------------------
// Kernel A: qkv = x @ w_qkv + b_qkv, split into Q (pre-scaled), K, V
// layout [b][h][n][hd]. Tile: 32 rows x 288 cols per 256-thread block.
// Thread (tr=t>>5, tc=t&31) owns rows tr+8i (i<4), cols tc+32j (j<9).
// ---------------------------------------------------------------------------
__global__ __launch_bounds__(256) void qkv_kernel(
    const float* __restrict__ x, const float* __restrict__ w,
    const float* __restrict__ bias,
    float* __restrict__ Q, float* __restrict__ K, float* __restrict__ V) {
  __shared__ float xs[32 * 96];
  const int t = threadIdx.x;
  const long rowBase = (long)blockIdx.x * 32;

  // stage x tile (contiguous 32*96 floats)
  {
    const float4* src = (const float4*)(x + rowBase * 96);
    float4* dst = (float4*)xs;
    for (int i = t; i < 32 * 96 / 4; i += 256) dst[i] = src[i];
  }
  __syncthreads();

  const int tc = t & 31, tr = t >> 5;
  float acc[4][9];
#pragma unroll
  for (int i = 0; i < 4; ++i)
#pragma unroll
    for (int j = 0; j < 9; ++j) acc[i][j] = 0.f;

  for (int c = 0; c < 96; ++c) {
    float wv[9];
    const float* wrow = w + c * QKV_COLS + tc;
#pragma unroll
    for (int j = 0; j < 9; ++j) wv[j] = wrow[32 * j];
#pragma unroll
    for (int i = 0; i < 4; ++i) {
      const float xv = xs[(tr + 8 * i) * 96 + c];
#pragma unroll
      for (int j = 0; j < 9; ++j) acc[i][j] = fmaf(xv, wv[j], acc[i][j]);
    }
  }

  const float scale = 0.17677669529663687f;  // hd^-0.5
#pragma unroll
  for (int i = 0; i < 4; ++i) {
    const long r = rowBase + tr + 8 * i;
    const int b = (int)(r / N_TOK);
    const int n = (int)(r % N_TOK);
#pragma unroll
    for (int j = 0; j < 9; ++j) {
      const int col = tc + 32 * j;
      const int which = j / 3;  // 0=q 1=k 2=v  (col/96)
      const int h = j % 3;      // (col%96)/32
      const float v = acc[i][j] + bias[col];
      const long dst = (((long)b * HEADS + h) * N_TOK + n) * HD + tc;
      if (which == 0)      Q[dst] = v * scale;
      else if (which == 1) K[dst] = v;
      else                 V[dst] = v;
    }
  }
}

// ---------------------------------------------------------------------------
// Kernel B: attention for one (b,h) per block. K,V + bias slice in LDS.
// One query row per thread (t < 343). Softmax without max-subtraction
// (logits are O(1); mask=-100 underflows to ~0, same as reference).
// rel idx: (di+6)*169 + (dj+6)*13 + (dk+6) = base_n + 1098 - base_m.
// ---------------------------------------------------------------------------
__global__ __launch_bounds__(384) void attn_kernel(
    const float* __restrict__ Q, const float* __restrict__ K,
    const float* __restrict__ V, const float* __restrict__ bias_table,
    const float* __restrict__ mask, float* __restrict__ out2 /*[B][N][C]*/) {
  __shared__ float Ks[N_TOK * HD];
  __shared__ float Vs[N_TOK * HD];
  __shared__ float bs[2197];

  const int blk = blockIdx.x;       // b*HEADS + h
  const int b = blk / HEADS;
  const int h = blk % HEADS;
  const int t = threadIdx.x;

  const float* Kg = K + (long)blk * (N_TOK * HD);
  const float* Vg = V + (long)blk * (N_TOK * HD);
  {
    const float4* ks = (const float4*)Kg;
    const float4* vs = (const float4*)Vg;
    float4* kd = (float4*)Ks;
    float4* vd = (float4*)Vs;
    for (int i = t; i < N_TOK * HD / 4; i += 384) { kd[i] = ks[i]; vd[i] = vs[i]; }
  }
  for (int i = t; i < 2197; i += 384) bs[i] = bias_table[i * HEADS + h];
  __syncthreads();

  if (t < N_TOK) {
    const int n = t;
    float q[HD];
    {
      const float4* qg = (const float4*)(Q + (long)blk * (N_TOK * HD) + n * HD);
#pragma unroll
      for (int i = 0; i < 8; ++i) {
        float4 f = qg[i];
        q[4 * i + 0] = f.x; q[4 * i + 1] = f.y;
        q[4 * i + 2] = f.z; q[4 * i + 3] = f.w;
      }
    }
    const int base_n = (n / 49) * 169 + ((n / 7) % 7) * 13 + (n % 7) + 1098;
    const int w = b & (NW - 1);
    const float* mrow = mask + ((long)w * N_TOK + n) * N_TOK;

    float l = 0.f;
    float acc[HD];
#pragma unroll
    for (int d = 0; d < HD; ++d) acc[d] = 0.f;

    for (int m = 0; m < N_TOK; ++m) {
      const float* km = Ks + m * HD;
      float dot = 0.f;
#pragma unroll
      for (int d = 0; d < HD; ++d) dot = fmaf(q[d], km[d], dot);
      const int base_m = (m / 49) * 169 + ((m / 7) % 7) * 13 + (m % 7);
      const float logit = dot + bs[base_n - base_m] + mrow[m];
      const float p = __expf(logit);
      l += p;
      const float* vm = Vs + m * HD;
#pragma unroll
      for (int d = 0; d < HD; ++d) acc[d] = fmaf(p, vm[d], acc[d]);
    }

    const float inv = 1.f / l;
    float* orow = out2 + ((long)b * N_TOK + n) * C_DIM + h * HD;
#pragma unroll
    for (int d = 0; d < HD; d += 4) {
      float4 o;
      o.x = acc[d] * inv; o.y = acc[d + 1] * inv;
      o.z = acc[d + 2] * inv; o.w = acc[d + 3] * inv;
      *(float4*)(orow + d) = o;
    }
  }
}

// ---------------------------------------------------------------------------
// Kernel C: out = attn_out @ w_proj + b_proj. Tile 32 rows x 96 cols.
// Thread (tr,tc): rows tr+8i (i<4), cols tc+32j (j<3).
// ---------------------------------------------------------------------------
__global__ __launch_bounds__(256) void proj_kernel(
    const float* __restrict__ a2, const float* __restrict__ w,
    const float* __restrict__ bias, float* __restrict__ out) {
  __shared__ float xs[32 * 96];
  const int t = threadIdx.x;
  const long rowBase = (long)blockIdx.x * 32;
  {
    const float4* src = (const float4*)(a2 + rowBase * 96);
    float4* dst = (float4*)xs;
    for (int i = t; i < 32 * 96 / 4; i += 256) dst[i] = src[i];
  }
  __syncthreads();

  const int tc = t & 31, tr = t >> 5;
  float acc[4][3];
#pragma unroll
  for (int i = 0; i < 4; ++i)
#pragma unroll
    for (int j = 0; j < 3; ++j) acc[i][j] = 0.f;

  for (int c = 0; c < 96; ++c) {
    float wv[3];
    const float* wrow = w + c * C_DIM + tc;
#pragma unroll
    for (int j = 0; j < 3; ++j) wv[j] = wrow[32 * j];
#pragma unroll
    for (int i = 0; i < 4; ++i) {
      const float xv = xs[(tr + 8 * i) * 96 + c];
#pragma unroll
      for (int j = 0; j < 3; ++j) acc[i][j] = fmaf(xv, wv[j], acc[i][j]);
    }
  }

#pragma unroll
  for (int i = 0; i < 4; ++i) {
    const long r = rowBase + tr + 8 * i;
#pragma unroll
    for (int j = 0; j < 3; ++j) {
      const int col = tc + 32 * j;
      out[r * C_DIM + col] = acc[i][j] + bias[col];
    }
  }
}

// ---------------------------------------------------------------------------
extern "C" void kernel_launch(void* const* d_in, const int* in_sizes, int n_in,
                              void* d_out, int out_size, void* d_ws, size_t ws_size,
                              hipStream_t stream) {
  const float* x          = (const float*)d_in[0];
  const float* mask       = (const float*)d_in[1];
  const float* w_qkv      = (const float*)d_in[2];
  const float* b_qkv      = (const float*)d_in[3];
  const float* bias_table = (const float*)d_in[4];
  const float* w_proj     = (const float*)d_in[5];
  const float* b_proj     = (const float*)d_in[6];
  float* out = (float*)d_out;

  float* ws = (float*)d_ws;
  float* Q  = ws;
  float* Kb = Q + QKV_ELEMS;
  float* Vb = Kb + QKV_ELEMS;
  float* X2 = Vb + QKV_ELEMS;  // [B][N][C] attention output

  const int rowBlocks = (B_SZ * N_TOK) / 32;  // 2744
  qkv_kernel<<<rowBlocks, 256, 0, stream>>>(x, w_qkv, b_qkv, Q, Kb, Vb);
  attn_kernel<<<B_SZ * HEADS, 384, 0, stream>>>(Q, Kb, Vb, bias_table, mask, X2);
  proj_kernel<<<rowBlocks, 256, 0, stream>>>(X2, w_proj, b_proj, out);
}

// Round 3
// 291.978 us; speedup vs baseline: 2.2774x; 2.2774x over previous
//
#include <hip/hip_runtime.h>

#define N_TOK 343
#define NP 352        // padded tokens (22*16)
#define C_DIM 96
#define HEADS 3
#define HD 32
#define B_SZ 256
#define NW 32
#define QKV_COLS 288

#define QKV_ELEMS (B_SZ * HEADS * N_TOK * HD)  // 8429568

typedef _Float16 f16;
typedef _Float16 f16x2 __attribute__((ext_vector_type(2)));
typedef _Float16 f16x4 __attribute__((ext_vector_type(4)));
typedef _Float16 f16x8 __attribute__((ext_vector_type(8)));
typedef __fp16 fp16x2 __attribute__((ext_vector_type(2)));  // cvt_pkrtz native type
typedef float f32x4 __attribute__((ext_vector_type(4)));

// ---------------------------------------------------------------------------
// Kernel A: qkv = x @ w_qkv + b_qkv -> f16 Q (pre-scaled), K, V  [b][h][n][32]
// ---------------------------------------------------------------------------
__global__ __launch_bounds__(256) void qkv_kernel(
    const float* __restrict__ x, const float* __restrict__ w,
    const float* __restrict__ bias,
    f16* __restrict__ Q, f16* __restrict__ K, f16* __restrict__ V) {
  __shared__ float xs[32 * 96];
  const int t = threadIdx.x;
  const long rowBase = (long)blockIdx.x * 32;

  {
    const float4* src = (const float4*)(x + rowBase * 96);
    float4* dst = (float4*)xs;
    for (int i = t; i < 32 * 96 / 4; i += 256) dst[i] = src[i];
  }
  __syncthreads();

  const int tc = t & 31, tr = t >> 5;
  float acc[4][9];
#pragma unroll
  for (int i = 0; i < 4; ++i)
#pragma unroll
    for (int j = 0; j < 9; ++j) acc[i][j] = 0.f;

  for (int c = 0; c < 96; ++c) {
    float wv[9];
    const float* wrow = w + c * QKV_COLS + tc;
#pragma unroll
    for (int j = 0; j < 9; ++j) wv[j] = wrow[32 * j];
#pragma unroll
    for (int i = 0; i < 4; ++i) {
      const float xv = xs[(tr + 8 * i) * 96 + c];
#pragma unroll
      for (int j = 0; j < 9; ++j) acc[i][j] = fmaf(xv, wv[j], acc[i][j]);
    }
  }

  const float scale = 0.17677669529663687f;  // hd^-0.5
#pragma unroll
  for (int i = 0; i < 4; ++i) {
    const long r = rowBase + tr + 8 * i;
    const int b = (int)(r / N_TOK);
    const int n = (int)(r % N_TOK);
#pragma unroll
    for (int j = 0; j < 9; ++j) {
      const int col = tc + 32 * j;
      const int which = j / 3;
      const int h = j % 3;
      const float v = acc[i][j] + bias[col];
      const long dst = (((long)b * HEADS + h) * N_TOK + n) * HD + tc;
      if (which == 0)      Q[dst] = (f16)(v * scale);
      else if (which == 1) K[dst] = (f16)v;
      else                 V[dst] = (f16)v;
    }
  }
}

// ---------------------------------------------------------------------------
// Kernel P: fused bias+mask -> CMB[w][h][343][352] f16.  Pad keys get -1000
// (exp underflows to exactly 0, so padded keys need no special handling).
// rel idx: base(n) - base(m) + 1098, base(n)=(n/49)*169+((n/7)%7)*13+n%7.
// ---------------------------------------------------------------------------
__global__ __launch_bounds__(256) void cmb_kernel(
    const float* __restrict__ mask, const float* __restrict__ bias_table,
    f16* __restrict__ cmb) {
  const long e = (long)blockIdx.x * 256 + threadIdx.x;
  if (e >= (long)NW * HEADS * N_TOK * NP) return;
  const int key = (int)(e % NP);
  const long rowid = e / NP;
  const int q = (int)(rowid % N_TOK);
  const int wh = (int)(rowid / N_TOK);
  const int h = wh % HEADS;
  const int w = wh / HEADS;
  float val;
  if (key < N_TOK) {
    const int bn = (q / 49) * 169 + ((q / 7) % 7) * 13 + (q % 7);
    const int bm = (key / 49) * 169 + ((key / 7) % 7) * 13 + (key % 7);
    val = bias_table[(bn - bm + 1098) * HEADS + h] +
          mask[((long)w * N_TOK + q) * N_TOK + key];
  } else {
    val = -1000.f;
  }
  cmb[e] = (f16)val;
}

// ---------------------------------------------------------------------------
// Kernel B: MFMA attention. One block per (b,h); 8 waves; each wave owns
// Q-tiles qt = wave, wave+8, ... (22 tiles of 16 rows).
// S^T = K_tile * Q^T via mfma_f32_16x16x32_f16 (lane: key=4g+r, q=c).
// P (f16) via per-wave LDS buffer -> B-frag of O^T = V^T * P^T.
// ---------------------------------------------------------------------------
__global__ __launch_bounds__(512) void attn_kernel(
    const f16* __restrict__ Qh, const f16* __restrict__ Kh,
    const f16* __restrict__ Vh, const f16* __restrict__ CMB,
    float* __restrict__ X2) {
  __shared__ f16 Ks[NP][40];     // 80B row stride: frag reads 2-way (free)
  __shared__ f16 Vt[HD][360];    // transposed V, 720B stride
  __shared__ f16 Pb[8][16][40];  // per-wave P buffer

  const int blk = blockIdx.x;
  const int b = blk / HEADS;
  const int h = blk % HEADS;
  const int tid = threadIdx.x;
  const int wave = tid >> 6;
  const int lane = tid & 63;
  const int c = lane & 15;     // q column within tile / d row for V-frag
  const int g = lane >> 4;     // k-chunk group

  const f16* Kg = Kh + (long)blk * (N_TOK * HD);
  const f16* Vg = Vh + (long)blk * (N_TOK * HD);
  const f16* Qg = Qh + (long)blk * (N_TOK * HD);

  // --- stage K (zero-padded rows) ---
  for (int u = tid; u < NP * 4; u += 512) {
    const int key = u >> 2, j = u & 3;
    f16x8 val = {0, 0, 0, 0, 0, 0, 0, 0};
    if (key < N_TOK) val = *(const f16x8*)(Kg + key * HD + j * 8);
    *(f16x8*)&Ks[key][j * 8] = val;
  }
  // --- stage V transposed ---
  for (int i = tid; i < N_TOK * 16; i += 512) {
    const int n = i >> 4, dp = i & 15;
    const f16x2 v2 = *(const f16x2*)(Vg + n * HD + dp * 2);
    Vt[2 * dp][n] = v2.x;
    Vt[2 * dp + 1][n] = v2.y;
  }
  for (int i = tid; i < HD * 9; i += 512) Vt[i / 9][N_TOK + i % 9] = (f16)0;
  __syncthreads();

  const int w = b & (NW - 1);
  const f32x4 zero = {0.f, 0.f, 0.f, 0.f};

  for (int qt = wave; qt < NP / 16; qt += 8) {
    const int q = qt * 16 + c;
    const int qrow = (q < N_TOK) ? q : (N_TOK - 1);
    const f16x8 qf = *(const f16x8*)(Qg + qrow * HD + g * 8);
    const f16* cmrow = CMB + ((long)(w * HEADS + h) * N_TOK + qrow) * NP;

    f32x4 acc0 = zero, acc1 = zero;
    float lsum = 0.f;

    for (int kt = 0; kt < NP / 32; ++kt) {
      const f16x8 kf0 = *(const f16x8*)&Ks[32 * kt + c][g * 8];
      const f16x8 kf1 = *(const f16x8*)&Ks[32 * kt + 16 + c][g * 8];
      const f16x4 cm0 = *(const f16x4*)(cmrow + 32 * kt + 4 * g);
      const f16x4 cm1 = *(const f16x4*)(cmrow + 32 * kt + 16 + 4 * g);

      const f32x4 s0 = __builtin_amdgcn_mfma_f32_16x16x32_f16(kf0, qf, zero, 0, 0, 0);
      const f32x4 s1 = __builtin_amdgcn_mfma_f32_16x16x32_f16(kf1, qf, zero, 0, 0, 0);

      float p0[4], p1[4];
#pragma unroll
      for (int r = 0; r < 4; ++r) {
        p0[r] = __expf(s0[r] + (float)cm0[r]);
        p1[r] = __expf(s1[r] + (float)cm1[r]);
        lsum += p0[r] + p1[r];
      }
      const f16x2 l0 = __builtin_bit_cast(f16x2, __builtin_amdgcn_cvt_pkrtz(p0[0], p0[1]));
      const f16x2 h0 = __builtin_bit_cast(f16x2, __builtin_amdgcn_cvt_pkrtz(p0[2], p0[3]));
      const f16x2 l1 = __builtin_bit_cast(f16x2, __builtin_amdgcn_cvt_pkrtz(p1[0], p1[1]));
      const f16x2 h1 = __builtin_bit_cast(f16x2, __builtin_amdgcn_cvt_pkrtz(p1[2], p1[3]));
      f16x4 pk0, pk1;
      pk0.x = l0.x; pk0.y = l0.y; pk0.z = h0.x; pk0.w = h0.y;
      pk1.x = l1.x; pk1.y = l1.y; pk1.z = h1.x; pk1.w = h1.y;
      *(f16x4*)&Pb[wave][c][4 * g] = pk0;        // keys 4g+r   (tile a=0)
      *(f16x4*)&Pb[wave][c][16 + 4 * g] = pk1;   // keys 16+4g+r (tile a=1)
      __builtin_amdgcn_wave_barrier();

      const f16x8 pf = *(const f16x8*)&Pb[wave][c][8 * g];
      const f16x8 vf0 = *(const f16x8*)&Vt[c][32 * kt + 8 * g];
      const f16x8 vf1 = *(const f16x8*)&Vt[16 + c][32 * kt + 8 * g];
      acc0 = __builtin_amdgcn_mfma_f32_16x16x32_f16(vf0, pf, acc0, 0, 0, 0);
      acc1 = __builtin_amdgcn_mfma_f32_16x16x32_f16(vf1, pf, acc1, 0, 0, 0);
      __builtin_amdgcn_wave_barrier();
    }

    // row sum over g-groups (lanes c, c+16, c+32, c+48)
    lsum += __shfl_xor(lsum, 16);
    lsum += __shfl_xor(lsum, 32);
    const float inv = 1.f / lsum;

    if (q < N_TOK) {
      float* orow = X2 + ((long)b * N_TOK + q) * C_DIM + h * HD;
      float4 o0, o1;
      o0.x = acc0[0] * inv; o0.y = acc0[1] * inv;
      o0.z = acc0[2] * inv; o0.w = acc0[3] * inv;
      o1.x = acc1[0] * inv; o1.y = acc1[1] * inv;
      o1.z = acc1[2] * inv; o1.w = acc1[3] * inv;
      *(float4*)(orow + 4 * g) = o0;        // d = 4g+r       (half 0)
      *(float4*)(orow + 16 + 4 * g) = o1;   // d = 16+4g+r    (half 1)
    }
  }
}

// ---------------------------------------------------------------------------
// Kernel C: out = X2 @ w_proj + b_proj (f32)
// ---------------------------------------------------------------------------
__global__ __launch_bounds__(256) void proj_kernel(
    const float* __restrict__ a2, const float* __restrict__ w,
    const float* __restrict__ bias, float* __restrict__ out) {
  __shared__ float xs[32 * 96];
  const int t = threadIdx.x;
  const long rowBase = (long)blockIdx.x * 32;
  {
    const float4* src = (const float4*)(a2 + rowBase * 96);
    float4* dst = (float4*)xs;
    for (int i = t; i < 32 * 96 / 4; i += 256) dst[i] = src[i];
  }
  __syncthreads();

  const int tc = t & 31, tr = t >> 5;
  float acc[4][3];
#pragma unroll
  for (int i = 0; i < 4; ++i)
#pragma unroll
    for (int j = 0; j < 3; ++j) acc[i][j] = 0.f;

  for (int c = 0; c < 96; ++c) {
    float wv[3];
    const float* wrow = w + c * C_DIM + tc;
#pragma unroll
    for (int j = 0; j < 3; ++j) wv[j] = wrow[32 * j];
#pragma unroll
    for (int i = 0; i < 4; ++i) {
      const float xv = xs[(tr + 8 * i) * 96 + c];
#pragma unroll
      for (int j = 0; j < 3; ++j) acc[i][j] = fmaf(xv, wv[j], acc[i][j]);
    }
  }

#pragma unroll
  for (int i = 0; i < 4; ++i) {
    const long r = rowBase + tr + 8 * i;
#pragma unroll
    for (int j = 0; j < 3; ++j) {
      const int col = tc + 32 * j;
      out[r * C_DIM + col] = acc[i][j] + bias[col];
    }
  }
}

// ---------------------------------------------------------------------------
extern "C" void kernel_launch(void* const* d_in, const int* in_sizes, int n_in,
                              void* d_out, int out_size, void* d_ws, size_t ws_size,
                              hipStream_t stream) {
  const float* x          = (const float*)d_in[0];
  const float* mask       = (const float*)d_in[1];
  const float* w_qkv      = (const float*)d_in[2];
  const float* b_qkv      = (const float*)d_in[3];
  const float* bias_table = (const float*)d_in[4];
  const float* w_proj     = (const float*)d_in[5];
  const float* b_proj     = (const float*)d_in[6];
  float* out = (float*)d_out;

  f16* Qh = (f16*)d_ws;
  f16* Kh = Qh + QKV_ELEMS;
  f16* Vh = Kh + QKV_ELEMS;
  float* X2 = (float*)(Vh + QKV_ELEMS);
  f16* CMB = (f16*)(X2 + (long)B_SZ * N_TOK * C_DIM);

  const int rowBlocks = (B_SZ * N_TOK) / 32;  // 2744
  const long cmbElems = (long)NW * HEADS * N_TOK * NP;
  const int cmbBlocks = (int)((cmbElems + 255) / 256);

  cmb_kernel<<<cmbBlocks, 256, 0, stream>>>(mask, bias_table, CMB);
  qkv_kernel<<<rowBlocks, 256, 0, stream>>>(x, w_qkv, b_qkv, Qh, Kh, Vh);
  attn_kernel<<<B_SZ * HEADS, 512, 0, stream>>>(Qh, Kh, Vh, CMB, X2);
  proj_kernel<<<rowBlocks, 256, 0, stream>>>(X2, w_proj, b_proj, out);
}

// Round 4
// 216.152 us; speedup vs baseline: 3.0763x; 1.3508x over previous
//
#include <hip/hip_runtime.h>

#define N_TOK 343
#define NP 352        // padded tokens (22*16)
#define C_DIM 96
#define HEADS 3
#define HD 32
#define B_SZ 256
#define NW 32
#define QKV_COLS 288

#define QKV_ELEMS (B_SZ * HEADS * N_TOK * HD)  // 8429568
#define X2_ELEMS ((long)B_SZ * N_TOK * C_DIM)  // 8429568
#define CMB_ELEMS ((long)NW * HEADS * N_TOK * NP)

typedef _Float16 f16;
typedef _Float16 f16x2 __attribute__((ext_vector_type(2)));
typedef _Float16 f16x4 __attribute__((ext_vector_type(4)));
typedef _Float16 f16x8 __attribute__((ext_vector_type(8)));
typedef float f32x4 __attribute__((ext_vector_type(4)));

// ---------------------------------------------------------------------------
// Kernel W: transpose+cast weights to f16. wt_qkv[col][k] (288x96),
// wt_proj[col][k] (96x96).
// ---------------------------------------------------------------------------
__global__ __launch_bounds__(256) void wprep_kernel(
    const float* __restrict__ w_qkv, const float* __restrict__ w_proj,
    f16* __restrict__ wt_qkv, f16* __restrict__ wt_proj) {
  const int e = blockIdx.x * 256 + threadIdx.x;
  if (e < QKV_COLS * 96) {
    const int cc = e / 96, k = e % 96;
    wt_qkv[e] = (f16)w_qkv[k * QKV_COLS + cc];
  } else {
    const int e2 = e - QKV_COLS * 96;
    if (e2 < 96 * 96) {
      const int cc = e2 / 96, k = e2 % 96;
      wt_proj[e2] = (f16)w_proj[k * 96 + cc];
    }
  }
}

// ---------------------------------------------------------------------------
// Kernel P: fused bias+mask -> CMB[w][h][343][352] f16.  Pad keys get -1000.
// ---------------------------------------------------------------------------
__global__ __launch_bounds__(256) void cmb_kernel(
    const float* __restrict__ mask, const float* __restrict__ bias_table,
    f16* __restrict__ cmb) {
  const long e = (long)blockIdx.x * 256 + threadIdx.x;
  if (e >= CMB_ELEMS) return;
  const int key = (int)(e % NP);
  const long rowid = e / NP;
  const int q = (int)(rowid % N_TOK);
  const int wh = (int)(rowid / N_TOK);
  const int h = wh % HEADS;
  const int w = wh / HEADS;
  float val;
  if (key < N_TOK) {
    const int bn = (q / 49) * 169 + ((q / 7) % 7) * 13 + (q % 7);
    const int bm = (key / 49) * 169 + ((key / 7) % 7) * 13 + (key % 7);
    val = bias_table[(bn - bm + 1098) * HEADS + h] +
          mask[((long)w * N_TOK + q) * N_TOK + key];
  } else {
    val = -1000.f;
  }
  cmb[e] = (f16)val;
}

// ---------------------------------------------------------------------------
// Kernel A: MFMA qkv. Block = 64 rows (4 waves x 16), full 288 cols.
// A-frag: x rows cast f32->f16 in-register. B-frag: wt_qkv (L2-resident).
// D frag: row = 4g+r (A row), col = c. which/h uniform per col-tile.
// ---------------------------------------------------------------------------
__global__ __launch_bounds__(256) void qkv_mfma_kernel(
    const float* __restrict__ x, const f16* __restrict__ wt,
    const float* __restrict__ bias,
    f16* __restrict__ Q, f16* __restrict__ K, f16* __restrict__ V) {
  const int tid = threadIdx.x;
  const int wave = tid >> 6, lane = tid & 63;
  const int c = lane & 15, g = lane >> 4;
  const long rowTile = (long)blockIdx.x * 64 + wave * 16;
  const long arow = rowTile + c;

  // 3 A-frags (k = ks*32 + g*8 .. +8), f32 -> f16
  f16x8 af[3];
#pragma unroll
  for (int ks = 0; ks < 3; ++ks) {
    const float* px = x + arow * 96 + ks * 32 + g * 8;
    const float4 lo = *(const float4*)px;
    const float4 hi = *(const float4*)(px + 4);
    f16x8 v;
    v[0] = (f16)lo.x; v[1] = (f16)lo.y; v[2] = (f16)lo.z; v[3] = (f16)lo.w;
    v[4] = (f16)hi.x; v[5] = (f16)hi.y; v[6] = (f16)hi.z; v[7] = (f16)hi.w;
    af[ks] = v;
  }

  // output rows 4g+r: window/token ids
  int bidx[4], nidx[4];
#pragma unroll
  for (int r = 0; r < 4; ++r) {
    const int row = (int)rowTile + 4 * g + r;
    bidx[r] = row / N_TOK;
    nidx[r] = row % N_TOK;
  }

  const f32x4 zero = {0.f, 0.f, 0.f, 0.f};
  const float scale = 0.17677669529663687f;  // hd^-0.5

#pragma unroll
  for (int ct = 0; ct < 18; ++ct) {
    f32x4 acc = zero;
#pragma unroll
    for (int ks = 0; ks < 3; ++ks) {
      const f16x8 bf = *(const f16x8*)(wt + (ct * 16 + c) * 96 + ks * 32 + g * 8);
      acc = __builtin_amdgcn_mfma_f32_16x16x32_f16(af[ks], bf, acc, 0, 0, 0);
    }
    const int col = ct * 16 + c;
    const int which = ct / 6;            // 0=q 1=k 2=v (uniform per ct)
    const int h = (ct % 6) >> 1;         // uniform per ct
    const int d = ((ct & 1) << 4) + c;   // col % 32
    const float bv = bias[col];
    f16* dst = (which == 0) ? Q : (which == 1) ? K : V;
    const float mult = (which == 0) ? scale : 1.0f;
#pragma unroll
    for (int r = 0; r < 4; ++r) {
      const float v = (acc[r] + bv) * mult;
      dst[(((long)bidx[r] * HEADS + h) * N_TOK + nidx[r]) * HD + d] = (f16)v;
    }
  }
}

// ---------------------------------------------------------------------------
// Kernel B: MFMA attention (unchanged except f16 X2 output).
// ---------------------------------------------------------------------------
__global__ __launch_bounds__(512) void attn_kernel(
    const f16* __restrict__ Qh, const f16* __restrict__ Kh,
    const f16* __restrict__ Vh, const f16* __restrict__ CMB,
    f16* __restrict__ X2h) {
  __shared__ f16 Ks[NP][40];
  __shared__ f16 Vt[HD][360];
  __shared__ f16 Pb[8][16][40];

  const int blk = blockIdx.x;
  const int b = blk / HEADS;
  const int h = blk % HEADS;
  const int tid = threadIdx.x;
  const int wave = tid >> 6;
  const int lane = tid & 63;
  const int c = lane & 15;
  const int g = lane >> 4;

  const f16* Kg = Kh + (long)blk * (N_TOK * HD);
  const f16* Vg = Vh + (long)blk * (N_TOK * HD);
  const f16* Qg = Qh + (long)blk * (N_TOK * HD);

  for (int u = tid; u < NP * 4; u += 512) {
    const int key = u >> 2, j = u & 3;
    f16x8 val = {0, 0, 0, 0, 0, 0, 0, 0};
    if (key < N_TOK) val = *(const f16x8*)(Kg + key * HD + j * 8);
    *(f16x8*)&Ks[key][j * 8] = val;
  }
  for (int i = tid; i < N_TOK * 16; i += 512) {
    const int n = i >> 4, dp = i & 15;
    const f16x2 v2 = *(const f16x2*)(Vg + n * HD + dp * 2);
    Vt[2 * dp][n] = v2.x;
    Vt[2 * dp + 1][n] = v2.y;
  }
  for (int i = tid; i < HD * 9; i += 512) Vt[i / 9][N_TOK + i % 9] = (f16)0;
  __syncthreads();

  const int w = b & (NW - 1);
  const f32x4 zero = {0.f, 0.f, 0.f, 0.f};

  for (int qt = wave; qt < NP / 16; qt += 8) {
    const int q = qt * 16 + c;
    const int qrow = (q < N_TOK) ? q : (N_TOK - 1);
    const f16x8 qf = *(const f16x8*)(Qg + qrow * HD + g * 8);
    const f16* cmrow = CMB + ((long)(w * HEADS + h) * N_TOK + qrow) * NP;

    f32x4 acc0 = zero, acc1 = zero;
    float lsum = 0.f;

    for (int kt = 0; kt < NP / 32; ++kt) {
      const f16x8 kf0 = *(const f16x8*)&Ks[32 * kt + c][g * 8];
      const f16x8 kf1 = *(const f16x8*)&Ks[32 * kt + 16 + c][g * 8];
      const f16x4 cm0 = *(const f16x4*)(cmrow + 32 * kt + 4 * g);
      const f16x4 cm1 = *(const f16x4*)(cmrow + 32 * kt + 16 + 4 * g);

      const f32x4 s0 = __builtin_amdgcn_mfma_f32_16x16x32_f16(kf0, qf, zero, 0, 0, 0);
      const f32x4 s1 = __builtin_amdgcn_mfma_f32_16x16x32_f16(kf1, qf, zero, 0, 0, 0);

      float p0[4], p1[4];
#pragma unroll
      for (int r = 0; r < 4; ++r) {
        p0[r] = __expf(s0[r] + (float)cm0[r]);
        p1[r] = __expf(s1[r] + (float)cm1[r]);
        lsum += p0[r] + p1[r];
      }
      const f16x2 l0 = __builtin_bit_cast(f16x2, __builtin_amdgcn_cvt_pkrtz(p0[0], p0[1]));
      const f16x2 h0 = __builtin_bit_cast(f16x2, __builtin_amdgcn_cvt_pkrtz(p0[2], p0[3]));
      const f16x2 l1 = __builtin_bit_cast(f16x2, __builtin_amdgcn_cvt_pkrtz(p1[0], p1[1]));
      const f16x2 h1 = __builtin_bit_cast(f16x2, __builtin_amdgcn_cvt_pkrtz(p1[2], p1[3]));
      f16x4 pk0, pk1;
      pk0.x = l0.x; pk0.y = l0.y; pk0.z = h0.x; pk0.w = h0.y;
      pk1.x = l1.x; pk1.y = l1.y; pk1.z = h1.x; pk1.w = h1.y;
      *(f16x4*)&Pb[wave][c][4 * g] = pk0;
      *(f16x4*)&Pb[wave][c][16 + 4 * g] = pk1;
      __builtin_amdgcn_wave_barrier();

      const f16x8 pf = *(const f16x8*)&Pb[wave][c][8 * g];
      const f16x8 vf0 = *(const f16x8*)&Vt[c][32 * kt + 8 * g];
      const f16x8 vf1 = *(const f16x8*)&Vt[16 + c][32 * kt + 8 * g];
      acc0 = __builtin_amdgcn_mfma_f32_16x16x32_f16(vf0, pf, acc0, 0, 0, 0);
      acc1 = __builtin_amdgcn_mfma_f32_16x16x32_f16(vf1, pf, acc1, 0, 0, 0);
      __builtin_amdgcn_wave_barrier();
    }

    lsum += __shfl_xor(lsum, 16);
    lsum += __shfl_xor(lsum, 32);
    const float inv = 1.f / lsum;

    if (q < N_TOK) {
      f16* orow = X2h + ((long)b * N_TOK + q) * C_DIM + h * HD;
      f16x4 o0, o1;
#pragma unroll
      for (int r = 0; r < 4; ++r) {
        o0[r] = (f16)(acc0[r] * inv);
        o1[r] = (f16)(acc1[r] * inv);
      }
      *(f16x4*)(orow + 4 * g) = o0;
      *(f16x4*)(orow + 16 + 4 * g) = o1;
    }
  }
}

// ---------------------------------------------------------------------------
// Kernel C: MFMA proj. out = X2h @ wt_proj + b_proj (f32 out).
// ---------------------------------------------------------------------------
__global__ __launch_bounds__(256) void proj_mfma_kernel(
    const f16* __restrict__ X2h, const f16* __restrict__ wt,
    const float* __restrict__ bias, float* __restrict__ out) {
  const int tid = threadIdx.x;
  const int wave = tid >> 6, lane = tid & 63;
  const int c = lane & 15, g = lane >> 4;
  const long rowTile = (long)blockIdx.x * 64 + wave * 16;
  const long arow = rowTile + c;

  f16x8 af[3];
#pragma unroll
  for (int ks = 0; ks < 3; ++ks)
    af[ks] = *(const f16x8*)(X2h + arow * 96 + ks * 32 + g * 8);

  const f32x4 zero = {0.f, 0.f, 0.f, 0.f};
#pragma unroll
  for (int ct = 0; ct < 6; ++ct) {
    f32x4 acc = zero;
#pragma unroll
    for (int ks = 0; ks < 3; ++ks) {
      const f16x8 bf = *(const f16x8*)(wt + (ct * 16 + c) * 96 + ks * 32 + g * 8);
      acc = __builtin_amdgcn_mfma_f32_16x16x32_f16(af[ks], bf, acc, 0, 0, 0);
    }
    const int col = ct * 16 + c;
    const float bv = bias[col];
#pragma unroll
    for (int r = 0; r < 4; ++r)
      out[(rowTile + 4 * g + r) * 96 + col] = acc[r] + bv;
  }
}

// ---------------------------------------------------------------------------
extern "C" void kernel_launch(void* const* d_in, const int* in_sizes, int n_in,
                              void* d_out, int out_size, void* d_ws, size_t ws_size,
                              hipStream_t stream) {
  const float* x          = (const float*)d_in[0];
  const float* mask       = (const float*)d_in[1];
  const float* w_qkv      = (const float*)d_in[2];
  const float* b_qkv      = (const float*)d_in[3];
  const float* bias_table = (const float*)d_in[4];
  const float* w_proj     = (const float*)d_in[5];
  const float* b_proj     = (const float*)d_in[6];
  float* out = (float*)d_out;

  f16* Qh = (f16*)d_ws;
  f16* Kh = Qh + QKV_ELEMS;
  f16* Vh = Kh + QKV_ELEMS;
  f16* X2h = Vh + QKV_ELEMS;
  f16* CMB = X2h + X2_ELEMS;
  f16* WTQ = CMB + CMB_ELEMS;
  f16* WTP = WTQ + QKV_COLS * 96;

  const int cmbBlocks = (int)((CMB_ELEMS + 255) / 256);
  const int wBlocks = (QKV_COLS * 96 + 96 * 96 + 255) / 256;  // 144
  const int gemmBlocks = (B_SZ * N_TOK) / 64;                  // 1372

  wprep_kernel<<<wBlocks, 256, 0, stream>>>(w_qkv, w_proj, WTQ, WTP);
  cmb_kernel<<<cmbBlocks, 256, 0, stream>>>(mask, bias_table, CMB);
  qkv_mfma_kernel<<<gemmBlocks, 256, 0, stream>>>(x, WTQ, b_qkv, Qh, Kh, Vh);
  attn_kernel<<<B_SZ * HEADS, 512, 0, stream>>>(Qh, Kh, Vh, CMB, X2h);
  proj_mfma_kernel<<<gemmBlocks, 256, 0, stream>>>(X2h, WTP, b_proj, out);
}